// Round 9
// baseline (143.575 us; speedup 1.0000x reference)
//
#include <hip/hip_runtime.h>
#include <math.h>

#define B_ 8
#define N_ 2048
#define C_ 512
#define G_ 64          // chunks per batch
#define L_ 32          // chunk length = N_/G_

// ---- workspace layout (in floats) ----
static const size_t OFF_V1   = 0;                    // 512
static const size_t OFF_V2   = OFF_V1 + 512;         // 512
static const size_t OFF_S1   = OFF_V2 + 512;         // 16384
static const size_t OFF_S2   = OFF_S1 + 16384;       // 16384
static const size_t OFF_Z    = OFF_S2 + 16384;       // 16384 sorted s2
static const size_t OFF_IDX  = OFF_Z + 16384;        // 16384 perm (int)
static const size_t OFF_P    = OFF_IDX + 16384;      // 16384 p = exp(z-m2)
static const size_t OFF_Q    = OFF_P + 16384;        // 16384 q = exp(0.2(z-m2))
static const size_t OFF_CHP  = OFF_Q + 16384;        // B*G*C = 262144 RAW chunk P sums
static const size_t OFF_CHQ  = OFF_CHP + 262144;     // 262144 RAW chunk Q sums
static const size_t OFF_EMR  = OFF_CHQ + 262144;     // 16384 emission row ids (int), bucket order
static const size_t OFF_EMP  = OFF_EMR + 16384;      // 16384 emission fP
static const size_t OFF_EMQ  = OFF_EMP + 16384;      // 16384 emission fQ
static const size_t OFF_POS  = OFF_EMQ + 16384;      // 8*2050 bucket starts (int)

// ---- float4 helpers ----
__device__ inline float4 f4z() { return make_float4(0.f, 0.f, 0.f, 0.f); }
__device__ inline float4 fma4(float s, float4 a, float4 c) {
    c.x = fmaf(s, a.x, c.x); c.y = fmaf(s, a.y, c.y);
    c.z = fmaf(s, a.z, c.z); c.w = fmaf(s, a.w, c.w); return c;
}
__device__ inline float4 add4(float4 a, float4 b) {
    return make_float4(a.x + b.x, a.y + b.y, a.z + b.z, a.w + b.w);
}
// fp*P + fq*(T - Q)
__device__ inline float4 comb4(float fp, float4 P, float fq, float4 T, float4 Q) {
    return make_float4(fp * P.x + fq * (T.x - Q.x),
                       fp * P.y + fq * (T.y - Q.y),
                       fp * P.z + fq * (T.z - Q.z),
                       fp * P.w + fq * (T.w - Q.w));
}

// K1: v1 = w @ a1, v2 = w @ a2
__global__ __launch_bounds__(64) void k_wa(const float* __restrict__ w,
                                           const float* __restrict__ a,
                                           float* __restrict__ v1, float* __restrict__ v2) {
    int k = blockIdx.x, lane = threadIdx.x;
    float acc1 = 0.f, acc2 = 0.f;
    for (int c = lane; c < C_; c += 64) {
        float wv = w[k * C_ + c];
        acc1 += wv * a[c];
        acc2 += wv * a[C_ + c];
    }
    for (int o = 32; o > 0; o >>= 1) { acc1 += __shfl_down(acc1, o); acc2 += __shfl_down(acc2, o); }
    if (lane == 0) { v1[k] = acc1; v2[k] = acc2; }
}

// K2: s1[r] = x[r,:]·v1, s2[r] = x[r,:]·v2
__global__ __launch_bounds__(256) void k_s(const float* __restrict__ x,
                                           const float* __restrict__ v1,
                                           const float* __restrict__ v2,
                                           float* __restrict__ s1, float* __restrict__ s2) {
    __shared__ __align__(16) float sv1[C_];
    __shared__ __align__(16) float sv2[C_];
    int tid = threadIdx.x;
    for (int c = tid; c < C_; c += 256) { sv1[c] = v1[c]; sv2[c] = v2[c]; }
    __syncthreads();
    int wave = tid >> 6, lane = tid & 63;
    int r = blockIdx.x * 4 + wave;
    const float4* xr  = reinterpret_cast<const float4*>(x + (size_t)r * C_);
    const float4* w1p = reinterpret_cast<const float4*>(sv1);
    const float4* w2p = reinterpret_cast<const float4*>(sv2);
    float a1 = 0.f, a2 = 0.f;
    #pragma unroll
    for (int half = 0; half < 2; ++half) {
        int c4 = lane + half * 64;
        float4 xv = xr[c4], w1 = w1p[c4], w2 = w2p[c4];
        a1 += xv.x*w1.x + xv.y*w1.y + xv.z*w1.z + xv.w*w1.w;
        a2 += xv.x*w2.x + xv.y*w2.y + xv.z*w2.z + xv.w*w2.w;
    }
    for (int o = 32; o > 0; o >>= 1) { a1 += __shfl_down(a1, o); a2 += __shfl_down(a2, o); }
    if (lane == 0) { s1[r] = a1; s2[r] = a2; }
}

// K3: rank-by-counting sort of s2 -> z (sorted), idx (perm), p, q
__global__ __launch_bounds__(256) void k_rank(const float* __restrict__ s2,
                                              float* __restrict__ z, int* __restrict__ idxArr,
                                              float* __restrict__ pArr, float* __restrict__ qArr) {
    __shared__ float sval[N_];
    __shared__ float sred[256];
    __shared__ int   srnk[256];
    int blk = blockIdx.x;
    int b = blk >> 5, grp = blk & 31;
    int tid = threadIdx.x;
    int le = tid & 63, qtr = tid >> 6;
    for (int i = tid; i < N_; i += 256) sval[i] = s2[(size_t)b * N_ + i];
    __syncthreads();
    int e = grp * 64 + le;
    float val = sval[e];
    int base = qtr * 512;
    int rank = 0;
    float mx = -3.4e38f;
    #pragma unroll 8
    for (int i = 0; i < 512; ++i) {
        int t = base + i;
        float v = sval[t];
        mx = fmaxf(mx, v);
        rank += (v < val) || (v == val && t < e);
    }
    srnk[tid] = rank;
    sred[tid] = mx;
    __syncthreads();
    for (int o = 128; o > 0; o >>= 1) {
        if (tid < o) sred[tid] = fmaxf(sred[tid], sred[tid + o]);
        __syncthreads();
    }
    float m2 = sred[0];
    if (qtr == 0) {
        int rk = srnk[le] + srnk[le + 64] + srnk[le + 128] + srnk[le + 192];
        float d = val - m2;
        size_t pos = (size_t)b * N_ + rk;
        z[pos]      = val;
        idxArr[pos] = e;
        pArr[pos]   = __expf(d);
        qArr[pos]   = __expf(0.2f * d);
    }
}

// K4: MERGED chunk + prep. Blocks 0..255: two chunk jobs each (512-thr halves).
// Blocks 256..263: per-batch prep (scan/split/bucket/scatter). Independent paths.
__global__ __launch_bounds__(1024) void k_cp(const float* __restrict__ x,
                                             const int* __restrict__ idxArr,
                                             const float* __restrict__ pArr,
                                             const float* __restrict__ qArr,
                                             const float* __restrict__ s1,
                                             const float* __restrict__ z,
                                             float* __restrict__ chP, float* __restrict__ chQ,
                                             int* __restrict__ emRow,
                                             float* __restrict__ emFP,
                                             float* __restrict__ emFQ,
                                             int* __restrict__ posStart) {
    union CpSM {
        struct {
            int srow[2][L_]; float spv[2][L_], sqv[2][L_];
            float4 partP[2][4][128], partQ[2][4][128];
        } ch;
        struct {
            float Ppre[N_ + 1], Qpre[N_ + 1], zv[N_];
            int cnt[N_ + 1], ps[N_ + 2];
            float wsP[16], wsQ[16], woP[16], woQ[16];
            int wsC[16], woC[16];
        } pr;
    };
    __shared__ CpSM sm;
    int gid = blockIdx.x, tid = threadIdx.x;
    int lane = tid & 63, wid = tid >> 6;

    if (gid < 256) {
        // ---------------- chunk path: jobs gid*2 + h ----------------
        int h = tid >> 9, t2 = tid & 511;
        int job = gid * 2 + h, b = job >> 6, g = job & 63;
        if (t2 < L_) {
            size_t jb = (size_t)b * N_ + g * L_ + t2;
            sm.ch.srow[h][t2] = idxArr[jb];
            sm.ch.spv[h][t2]  = pArr[jb];
            sm.ch.sqv[h][t2]  = qArr[jb];
        }
        __syncthreads();
        int rg = t2 >> 7, q = t2 & 127;
        const float4* xb4 = reinterpret_cast<const float4*>(x + (size_t)b * N_ * C_);
        float4 aP = f4z(), aQ = f4z();
        #pragma unroll
        for (int i = 0; i < 8; ++i) {
            int j = rg * 8 + i;
            float4 xv = xb4[(size_t)sm.ch.srow[h][j] * 128 + q];
            aP = fma4(sm.ch.spv[h][j], xv, aP);
            aQ = fma4(sm.ch.sqv[h][j], xv, aQ);
        }
        sm.ch.partP[h][rg][q] = aP;
        sm.ch.partQ[h][rg][q] = aQ;
        __syncthreads();
        if (t2 < 128) {
            float4 s = add4(add4(sm.ch.partP[h][0][t2], sm.ch.partP[h][1][t2]),
                            add4(sm.ch.partP[h][2][t2], sm.ch.partP[h][3][t2]));
            reinterpret_cast<float4*>(chP + (size_t)job * C_)[t2] = s;
        } else if (t2 < 256) {
            int qq = t2 - 128;
            float4 s = add4(add4(sm.ch.partQ[h][0][qq], sm.ch.partQ[h][1][qq]),
                            add4(sm.ch.partQ[h][2][qq], sm.ch.partQ[h][3][qq]));
            reinterpret_cast<float4*>(chQ + (size_t)job * C_)[qq] = s;
        }
    } else {
        // ---------------- prep path: batch b = gid - 256 ----------------
        int b = gid - 256;
        size_t ib = (size_t)b * N_;
        for (int i = tid; i < N_ + 1; i += 1024) sm.pr.cnt[i] = 0;
        sm.pr.zv[2*tid]   = z[ib + 2*tid];
        sm.pr.zv[2*tid+1] = z[ib + 2*tid+1];
        // A: scalar scans of p, q
        float p0 = pArr[ib + 2*tid], p1 = pArr[ib + 2*tid+1];
        float q0 = qArr[ib + 2*tid], q1 = qArr[ib + 2*tid+1];
        float pv = p0 + p1, qv = q0 + q1, pi = pv, qi = qv;
        for (int o = 1; o < 64; o <<= 1) {
            float tp = __shfl_up(pi, o), tq2 = __shfl_up(qi, o);
            if (lane >= o) { pi += tp; qi += tq2; }
        }
        if (lane == 63) { sm.pr.wsP[wid] = pi; sm.pr.wsQ[wid] = qi; }
        __syncthreads();
        if (wid == 0 && lane < 16) {
            float sp = sm.pr.wsP[lane], sq = sm.pr.wsQ[lane], ip = sp, iq = sq;
            for (int o = 1; o < 16; o <<= 1) {
                float tp = __shfl_up(ip, o), tq2 = __shfl_up(iq, o);
                if (lane >= o) { ip += tp; iq += tq2; }
            }
            sm.pr.woP[lane] = ip - sp; sm.pr.woQ[lane] = iq - sq;
        }
        __syncthreads();
        float inclP = pi + sm.pr.woP[wid], inclQ = qi + sm.pr.woQ[wid];
        float exclP = inclP - pv, exclQ = inclQ - qv;
        sm.pr.Ppre[2*tid] = exclP; sm.pr.Ppre[2*tid+1] = exclP + p0;
        sm.pr.Qpre[2*tid] = exclQ; sm.pr.Qpre[2*tid+1] = exclQ + q0;
        if (tid == 1023) { sm.pr.Ppre[N_] = inclP; sm.pr.Qpre[N_] = inclQ; }
        __syncthreads();
        // C: per-row split + factors + bucket count
        float m2 = sm.pr.zv[N_ - 1], Ptot = sm.pr.Ppre[N_];
        int kk[2], sl[2]; float fPv[2], fQv[2];
        #pragma unroll
        for (int h = 0; h < 2; ++h) {
            int rl = tid + h * 1024;
            float s1v = s1[ib + rl], thr = -s1v;
            int lo = 0, hi = N_;
            while (lo < hi) { int mid = (lo + hi) >> 1; if (sm.pr.zv[mid] >= thr) hi = mid; else lo = mid + 1; }
            float beta = s1v + m2, wPc, wQc;
            if (beta >= 0.f) { wPc = 1.f;                 wQc = __expf(-0.8f * beta); }
            else             { wPc = __expf(0.8f * beta); wQc = 1.f; }
            float inv = 1.f / (wPc * (Ptot - sm.pr.Ppre[lo]) + wQc * sm.pr.Qpre[lo]);
            fPv[h] = wPc * inv; fQv[h] = wQc * inv; kk[h] = lo;
            sl[h] = atomicAdd(&sm.pr.cnt[lo], 1);
        }
        __syncthreads();
        // D: scan bucket counts
        int c0 = sm.pr.cnt[2*tid], c1 = sm.pr.cnt[2*tid+1], cv = c0 + c1, ci = cv;
        for (int o = 1; o < 64; o <<= 1) { int t2 = __shfl_up(ci, o); if (lane >= o) ci += t2; }
        if (lane == 63) sm.pr.wsC[wid] = ci;
        __syncthreads();
        if (wid == 0 && lane < 16) {
            int sc = sm.pr.wsC[lane], ic = sc;
            for (int o = 1; o < 16; o <<= 1) { int t2 = __shfl_up(ic, o); if (lane >= o) ic += t2; }
            sm.pr.woC[lane] = ic - sc;
        }
        __syncthreads();
        int inclC = ci + sm.pr.woC[wid], exclC = inclC - cv;
        sm.pr.ps[2*tid] = exclC; sm.pr.ps[2*tid+1] = exclC + c0;
        if (tid == 1023) { sm.pr.ps[N_] = inclC; sm.pr.ps[N_+1] = inclC + sm.pr.cnt[N_]; }
        __syncthreads();
        posStart[b * 2050 + tid]        = sm.pr.ps[tid];
        posStart[b * 2050 + 1024 + tid] = sm.pr.ps[1024 + tid];
        if (tid < 2) posStart[b * 2050 + 2048 + tid] = sm.pr.ps[2048 + tid];
        // E: scatter emission records
        #pragma unroll
        for (int h = 0; h < 2; ++h) {
            int rl = tid + h * 1024;
            int u = sm.pr.ps[kk[h]] + sl[h];
            emRow[ib + u] = rl; emFP[ib + u] = fPv[h]; emFQ[ib + u] = fQv[h];
        }
    }
}

// K5: fused suffix walk + output emission. Computes its own chunk-level offsets
// from RAW chP/chQ (same descending accumulation order as the old k_choff).
__global__ __launch_bounds__(512) void k_fused(const float* __restrict__ x,
                                               const int* __restrict__ idxArr,
                                               const float* __restrict__ pArr,
                                               const float* __restrict__ qArr,
                                               const float* __restrict__ chP,
                                               const float* __restrict__ chQ,
                                               const int* __restrict__ emRow,
                                               const float* __restrict__ emFP,
                                               const float* __restrict__ emFQ,
                                               const int* __restrict__ posStart,
                                               float* __restrict__ out) {
    int bg = blockIdx.x, b = bg >> 6, g = bg & 63;
    int tid = threadIdx.x;
    __shared__ int   srow[L_];
    __shared__ float spv[L_], sqv[L_];
    __shared__ int   sps[L_ + 2];
    __shared__ int   semRow[N_];
    __shared__ float semFP[N_], semFQ[N_];
    __shared__ float4 partP[4][128], partQ[4][128];
    __shared__ float4 sOffP[128], sOffQ[128], sTq[128];
    // Phase A (parallel roles)
    if (tid < L_) {
        int j = g * L_ + tid;
        srow[tid] = idxArr[b * N_ + j];
        spv[tid]  = pArr[b * N_ + j];
        sqv[tid]  = qArr[b * N_ + j];
    } else if (tid >= 32 && tid < 32 + L_ + 2) {
        sps[tid - 32] = posStart[b * 2050 + g * L_ + (tid - 32)];
    } else if (tid >= 128 && tid < 256) {
        int q = tid - 128;
        const float4* cp4 = reinterpret_cast<const float4*>(chP) + (size_t)b * G_ * 128;
        float4 oP = f4z();
        for (int g2 = G_ - 1; g2 > g; --g2) oP = add4(oP, cp4[g2 * 128 + q]);
        sOffP[q] = oP;
    } else if (tid >= 256 && tid < 384) {
        int q = tid - 256;
        const float4* cq4 = reinterpret_cast<const float4*>(chQ) + (size_t)b * G_ * 128;
        float4 oQ = f4z();
        for (int g2 = G_ - 1; g2 > g; --g2) oQ = add4(oQ, cq4[g2 * 128 + q]);
        sOffQ[q] = oQ;
        float4 tq = oQ;
        for (int g2 = g; g2 >= 0; --g2) tq = add4(tq, cq4[g2 * 128 + q]);
        sTq[q] = tq;
    }
    __syncthreads();
    // Phase B: emission preload + x gathers + partial sums
    int uStart = sps[0];
    int uEnd   = (g == G_ - 1) ? sps[L_ + 1] : sps[L_];
    size_t ib = (size_t)b * N_;
    for (int u = uStart + tid; u < uEnd; u += 512) {
        int e = u - uStart;
        semRow[e] = emRow[ib + u];
        semFP[e]  = emFP [ib + u];
        semFQ[e]  = emFQ [ib + u];
    }
    int rg = tid >> 7, q = tid & 127;
    const float4* xb4 = reinterpret_cast<const float4*>(x + (size_t)b * N_ * C_);
    float4 xr4[8];
    #pragma unroll
    for (int i = 0; i < 8; ++i)
        xr4[i] = xb4[(size_t)srow[rg * 8 + i] * 128 + q];
    float4 sP = f4z(), sQ = f4z();
    #pragma unroll
    for (int i = 0; i < 8; ++i) {
        int j = rg * 8 + i;
        sP = fma4(spv[j], xr4[i], sP);
        sQ = fma4(sqv[j], xr4[i], sQ);
    }
    partP[rg][q] = sP;
    partQ[rg][q] = sQ;
    __syncthreads();
    // Phase C: group offsets + concurrent walks
    float4 runP = sOffP[q];
    float4 runQ = sOffQ[q];
    float4 tq4  = sTq[q];
    #pragma unroll
    for (int rg2 = 3; rg2 >= 1; --rg2) {
        if (rg2 > rg) { runP = add4(runP, partP[rg2][q]); runQ = add4(runQ, partQ[rg2][q]); }
    }
    float4* ob4 = reinterpret_cast<float4*>(out + (size_t)b * N_ * C_);
    if (g == G_ - 1 && rg == 3) {
        // bucket k == N: SufP = 0, PreQ = totQ
        for (int u = sps[L_]; u < sps[L_ + 1]; ++u) {
            int e = u - uStart;
            ob4[(size_t)semRow[e] * 128 + q] = comb4(semFP[e], runP, semFQ[e], tq4, runQ);
        }
    }
    #pragma unroll
    for (int t = 7; t >= 0; --t) {
        int j = rg * 8 + t;
        runP = fma4(spv[j], xr4[t], runP);
        runQ = fma4(sqv[j], xr4[t], runQ);
        for (int u = sps[j]; u < sps[j + 1]; ++u) {
            int e = u - uStart;
            ob4[(size_t)semRow[e] * 128 + q] = comb4(semFP[e], runP, semFQ[e], tq4, runQ);
        }
    }
}

extern "C" void kernel_launch(void* const* d_in, const int* in_sizes, int n_in,
                              void* d_out, int out_size, void* d_ws, size_t ws_size,
                              hipStream_t stream) {
    const float* x = (const float*)d_in[0];
    const float* w = (const float*)d_in[1];
    const float* a = (const float*)d_in[2];
    float* out = (float*)d_out;
    float* ws  = (float*)d_ws;

    float* v1   = ws + OFF_V1;
    float* v2   = ws + OFF_V2;
    float* s1   = ws + OFF_S1;
    float* s2   = ws + OFF_S2;
    float* zArr = ws + OFF_Z;
    int*   idxA = (int*)(ws + OFF_IDX);
    float* pArr = ws + OFF_P;
    float* qArr = ws + OFF_Q;
    float* chP  = ws + OFF_CHP;
    float* chQ  = ws + OFF_CHQ;
    int*   emR  = (int*)(ws + OFF_EMR);
    float* emP  = ws + OFF_EMP;
    float* emQ  = ws + OFF_EMQ;
    int*   pos  = (int*)(ws + OFF_POS);

    k_wa   <<<dim3(C_),      dim3(64),   0, stream>>>(w, a, v1, v2);
    k_s    <<<dim3(4096),    dim3(256),  0, stream>>>(x, v1, v2, s1, s2);
    k_rank <<<dim3(B_ * 32), dim3(256),  0, stream>>>(s2, zArr, idxA, pArr, qArr);
    k_cp   <<<dim3(264),     dim3(1024), 0, stream>>>(x, idxA, pArr, qArr, s1, zArr,
                                                      chP, chQ, emR, emP, emQ, pos);
    k_fused<<<dim3(B_ * G_), dim3(512),  0, stream>>>(x, idxA, pArr, qArr, chP, chQ,
                                                      emR, emP, emQ, pos, out);
}